// Round 3
// baseline (415.290 us; speedup 1.0000x reference)
//
#include <hip/hip_runtime.h>
#include <hip/hip_bf16.h>
#include <stdint.h>

// Problem constants
#define NPIX   32768      // 32 * 32 * 32 flattened vectors
#define DIM    256        // embedding dim
#define KCODE  1024       // codebook entries
#define BSTRIDE 262144    // 256*32*32 floats per batch in NCHW
#define OUT0_N 8388608    // 32*256*32*32
// d_out layout: [0 .. 8388607] quantized_st, [8388608] loss, [8388609 ..] indices(float)

// ---------------------------------------------------------------------------
// One numpy pw128 accumulator chain: r = v0^2; r += v_i^2 (15 adds), where
// the chain's elements are c0, c0+8, ..., c0+120 (element index * stride).
// ---------------------------------------------------------------------------
__device__ __forceinline__ float sqchain(const float* __restrict__ base, int stride, int c0) {
    float v = base[(size_t)c0 * stride];
    float r = __fmul_rn(v, v);
#pragma unroll
    for (int i = 1; i < 16; ++i) {
        float u = base[(size_t)(c0 + 8 * i) * stride];
        r = __fadd_rn(r, __fmul_rn(u, u));
    }
    return r;
}

// ---------------------------------------------------------------------------
// Kernel 1: numpy-pairwise sums of squares, coalesced.
// 4 threads per row; wave = 16 consecutive rows x 4 acc-groups (jg = lane>>4).
// Thread jg owns pw128 accumulator pairs (r[2jg], r[2jg+1]) of both halves.
// Tree: leaf g_jg = r[2jg]+r[2jg+1]; xor16 -> (g0+g1),(g2+g3); xor32 -> pw128;
// then lo+hi -> pw256. Bitwise identical to numpy pairwise (fp add commutes).
// Blocks 0..511 do pixels (stride-1024 rows, lanes coalesced over hw);
// blocks 512..527 do codebook rows (contiguous). Also inits ws64 + loss.
// ---------------------------------------------------------------------------
__global__ void vq_sums(const float* __restrict__ in, const float* __restrict__ emb,
                        float* __restrict__ sx_arr, float* __restrict__ se_arr,
                        float* __restrict__ loss_acc,
                        unsigned long long* __restrict__ ws64) {
    const int tid  = threadIdx.x;
    const int wave = tid >> 6;
    const int lane = tid & 63;
    const int jg   = lane >> 4;      // acc-group 0..3
    const int p    = lane & 15;      // row-in-wave
    const int n    = blockIdx.x * 64 + wave * 16 + p;
    if (blockIdx.x == 0 && tid == 0) *loss_acc = 0.0f;

    const float* base;
    int stride;
    if (n < NPIX) {
        base = in + (size_t)(n >> 10) * BSTRIDE + (n & 1023);
        stride = 1024;
    } else {
        base = emb + (size_t)(n - NPIX) * DIM;
        stride = 1;
    }
    const int c0 = 2 * jg;
    float glo = __fadd_rn(sqchain(base, stride, c0),       sqchain(base, stride, c0 + 1));
    float ghi = __fadd_rn(sqchain(base, stride, 128 + c0), sqchain(base, stride, 128 + c0 + 1));
    // combine leaf pairs across the 4 groups (exact pairwise tree):
    glo = __fadd_rn(glo, __shfl_xor(glo, 16, 64));
    glo = __fadd_rn(glo, __shfl_xor(glo, 32, 64));
    ghi = __fadd_rn(ghi, __shfl_xor(ghi, 16, 64));
    ghi = __fadd_rn(ghi, __shfl_xor(ghi, 32, 64));
    float s = __fadd_rn(glo, ghi);   // pw256 = pw128_lo + pw128_hi

    if (jg == 0) {
        if (n < NPIX) {
            sx_arr[n] = s;
            ws64[n] = 0xFFFFFFFFFFFFFFFFull;
        } else {
            se_arr[n - NPIX] = s;
        }
    }
}

// monotone float -> uint32 key (total order preserved for finite floats)
__device__ __forceinline__ unsigned int f2key(float f) {
    unsigned int u = __float_as_uint(f);
    return (u & 0x80000000u) ? ~u : (u | 0x80000000u);
}

// ---------------------------------------------------------------------------
// Kernel 2: split-K=4 argmin GEMM.
// grid = 1024: bx&255 -> n-tile of 128 pixels, bx>>8 -> k-quarter (256 codes).
// block = 256 threads (tx = k dim 16, ty = n dim 16), 8x8 microtile.
// Thread tx owns k-locals {tx*4+c, 64+tx*4+c : c=0..3}  -> b-frag b128 reads
// stride 16 B/lane -> 2-way bank aliasing only (free).
// launch_bounds(256,2): VGPR ~120 (NO spills — (256,4) forced 64 VGPR and
// 145 MB of scratch spill traffic in round 2). HW occupancy is resource-based:
// 120 VGPR < 128 cliff -> 4 waves/SIMD -> 4 blocks/CU -> grid fits in one wave.
// Accumulation: fp32 fmac over d = 0..255 ascending (bit-stable, verified).
// Fold: d = round(round(sx - 2m) + se); ties -> smaller k.
// ---------------------------------------------------------------------------
__global__ __launch_bounds__(256, 2)
void vq_argmin(const float* __restrict__ in, const float* __restrict__ emb,
               const float* __restrict__ sx_arr, const float* __restrict__ se_arr,
               unsigned long long* __restrict__ ws64) {
    const int bx = blockIdx.x;
    const int nt = bx & 255;
    const int ks = bx >> 8;
    const int n0 = nt << 7;          // 128 pixels per tile
    const int b  = n0 >> 10;
    const int hw0 = n0 & 1023;
    const int tid = threadIdx.x;
    const int tx = tid & 15;
    const int ty = tid >> 4;

    __shared__ float xs[16][128];
    __shared__ float es[16][132];     // +4 pad keeps transposed stores 2-way

    float bmin[8];
    int   bidx[8];
#pragma unroll
    for (int i = 0; i < 8; ++i) { bmin[i] = __uint_as_float(0x7f800000u); bidx[i] = 0; }

    const float* xbase = in + (size_t)b * BSTRIDE + hw0;

    for (int kt = 0; kt < 2; ++kt) {
        const int k0 = ks * 256 + kt * 128;

        float acc[8][8];
#pragma unroll
        for (int i = 0; i < 8; ++i)
#pragma unroll
            for (int j = 0; j < 8; ++j) acc[i][j] = 0.0f;

        for (int dc = 0; dc < 16; ++dc) {
            const int d0 = dc * 16;
            __syncthreads();   // previous-iteration readers done
            // stage x: 16 d x 128 n, coalesced along n
            {
                const int n4 = (tid & 31) * 4;
                const int dd = tid >> 5;
#pragma unroll
                for (int p = 0; p < 2; ++p) {
                    const int d = dd + 8 * p;
                    float4 v = *(const float4*)(xbase + (size_t)(d0 + d) * 1024 + n4);
                    *(float4*)&xs[d][n4] = v;
                }
            }
            // stage e (transposed): 128 k x 16 d
            {
                const int dq = (tid & 3) * 4;
                const int kb = tid >> 2;
#pragma unroll
                for (int p = 0; p < 2; ++p) {
                    const int k_l = kb + 64 * p;
                    float4 v = *(const float4*)(emb + (size_t)(k0 + k_l) * DIM + d0 + dq);
                    es[dq + 0][k_l] = v.x;
                    es[dq + 1][k_l] = v.y;
                    es[dq + 2][k_l] = v.z;
                    es[dq + 3][k_l] = v.w;
                }
            }
            __syncthreads();
#pragma unroll
            for (int d = 0; d < 16; ++d) {
                float4 a0 = *(const float4*)&xs[d][ty * 8];
                float4 a1 = *(const float4*)&xs[d][ty * 8 + 4];
                float4 b0 = *(const float4*)&es[d][tx * 4];        // k-locals tx*4..tx*4+3
                float4 b1 = *(const float4*)&es[d][tx * 4 + 64];   // k-locals 64+tx*4..+3
                float av[8] = {a0.x, a0.y, a0.z, a0.w, a1.x, a1.y, a1.z, a1.w};
                float bv[8] = {b0.x, b0.y, b0.z, b0.w, b1.x, b1.y, b1.z, b1.w};
#pragma unroll
                for (int i = 0; i < 8; ++i)
#pragma unroll
                    for (int j = 0; j < 8; ++j)
                        acc[i][j] += av[i] * bv[j];
            }
        }
        // fold this k-tile into running per-thread argmin (numpy-faithful rounding)
        float4 se0 = *(const float4*)(se_arr + k0 + tx * 4);
        float4 se1 = *(const float4*)(se_arr + k0 + 64 + tx * 4);
        float4 sx0 = *(const float4*)(sx_arr + n0 + ty * 8);
        float4 sx1 = *(const float4*)(sx_arr + n0 + ty * 8 + 4);
        float sxv[8] = {sx0.x, sx0.y, sx0.z, sx0.w, sx1.x, sx1.y, sx1.z, sx1.w};
        float sev[8] = {se0.x, se0.y, se0.z, se0.w, se1.x, se1.y, se1.z, se1.w};
#pragma unroll
        for (int i = 0; i < 8; ++i) {
#pragma unroll
            for (int j = 0; j < 8; ++j) {
                float t  = __fmaf_rn(-2.0f, acc[i][j], sxv[i]);  // round(sx - 2m)
                float dv = __fadd_rn(t, sev[j]);                 // round(+ se)
                int   k  = k0 + tx * 4 + (j & 3) + 64 * (j >> 2);
                if (dv < bmin[i]) { bmin[i] = dv; bidx[i] = k; } // j ascending == k ascending
            }
        }
    }

    // intra-wave reduction across tx (16 lanes per pixel-group), tie -> smaller k
#pragma unroll
    for (int i = 0; i < 8; ++i) {
        float v = bmin[i];
        int   k = bidx[i];
#pragma unroll
        for (int m = 1; m < 16; m <<= 1) {
            float ov = __shfl_xor(v, m, 16);
            int   ok = __shfl_xor(k, m, 16);
            if (ov < v || (ov == v && ok < k)) { v = ov; k = ok; }
        }
        if (tx == 0) {
            unsigned long long packed = ((unsigned long long)f2key(v) << 32) | (unsigned int)k;
            atomicMin(&ws64[n0 + ty * 8 + i], packed);
        }
    }
}

// ---------------------------------------------------------------------------
// Kernel 3: gather quantized rows, write straight-through output + indices,
// accumulate loss sum. grid = 256 blocks x 256 threads, 128 n per block.
// ---------------------------------------------------------------------------
__global__ void vq_write(const float* __restrict__ in, const float* __restrict__ emb,
                         const unsigned long long* __restrict__ ws64,
                         float* __restrict__ out0, float* __restrict__ out2,
                         float* __restrict__ loss_acc) {
    const int nt = blockIdx.x;
    const int n0 = nt << 7;
    const int b  = n0 >> 10;
    const int hw0 = n0 & 1023;
    const int tid = threadIdx.x;
    const int n_l = tid & 127;
    const int ch0 = tid >> 7;

    const int k = (int)(unsigned int)(ws64[n0 + n_l] & 0xFFFFFFFFull);
    if (tid < 128) out2[n0 + tid] = (float)k;

    const float* xrow = in  + (size_t)b * BSTRIDE + hw0 + n_l;
    float*       orow = out0 + (size_t)b * BSTRIDE + hw0 + n_l;
    const float* erow = emb + (size_t)k * DIM;

    float lsum = 0.0f;
    for (int it = 0; it < 128; ++it) {
        const int ch = it * 2 + ch0;
        float x = xrow[(size_t)ch * 1024];
        float q = erow[ch];
        float df = __fsub_rn(q, x);                 // round(q - x)
        orow[(size_t)ch * 1024] = __fadd_rn(x, df); // straight-through value
        lsum = __fadd_rn(lsum, __fmul_rn(df, df));
    }
    // block reduction: wave shuffle then LDS across 4 waves
#pragma unroll
    for (int off = 32; off >= 1; off >>= 1)
        lsum += __shfl_down(lsum, off, 64);
    __shared__ float wsum[4];
    if ((tid & 63) == 0) wsum[tid >> 6] = lsum;
    __syncthreads();
    if (tid == 0) {
        float t = wsum[0] + wsum[1] + wsum[2] + wsum[3];
        atomicAdd(loss_acc, t);
    }
}

// ---------------------------------------------------------------------------
// Kernel 4: finalize loss. mean = sum * 2^-23 (exact), loss = e + 0.25*e.
// ---------------------------------------------------------------------------
__global__ void vq_loss(const float* __restrict__ loss_acc, float* __restrict__ out1) {
    float s = *loss_acc;
    float e = s * (1.0f / 8388608.0f);      // division by 2^23, exact scaling
    out1[0] = __fadd_rn(e, __fmul_rn(0.25f, e));
}

extern "C" void kernel_launch(void* const* d_in, const int* in_sizes, int n_in,
                              void* d_out, int out_size, void* d_ws, size_t ws_size,
                              hipStream_t stream) {
    const float* in  = (const float*)d_in[0];
    const float* emb = (const float*)d_in[1];
    float* out = (float*)d_out;

    unsigned long long* ws64 = (unsigned long long*)d_ws;          // 32768 * 8 B
    float* wsf     = (float*)((char*)d_ws + NPIX * sizeof(unsigned long long));
    float* lossacc = wsf;                 // [0]
    float* sx_arr  = wsf + 256;           // 32768 floats
    float* se_arr  = wsf + 256 + NPIX;    // 1024 floats

    // vq_sums also inits ws64 (argmin slots) and the loss accumulator.
    vq_sums<<<(NPIX + KCODE) / 64, 256, 0, stream>>>(in, emb, sx_arr, se_arr, lossacc, ws64);
    vq_argmin<<<1024, 256, 0, stream>>>(in, emb, sx_arr, se_arr, ws64);
    vq_write<<<256, 256, 0, stream>>>(in, emb, ws64, out, out + OUT0_N + 1, lossacc);
    vq_loss<<<1, 1, 0, stream>>>(lossacc, out + OUT0_N);
}

// Round 4
// 368.472 us; speedup vs baseline: 1.1271x; 1.1271x over previous
//
#include <hip/hip_runtime.h>
#include <hip/hip_bf16.h>
#include <stdint.h>

// Problem constants
#define NPIX   32768      // 32 * 32 * 32 flattened vectors
#define DIM    256        // embedding dim
#define KCODE  1024       // codebook entries
#define BSTRIDE 262144    // 256*32*32 floats per batch in NCHW
#define OUT0_N 8388608    // 32*256*32*32
// d_out layout: [0 .. 8388607] quantized_st, [8388608] loss, [8388609 ..] indices(float)

// ---------------------------------------------------------------------------
// One numpy pw128 accumulator chain: r = v0^2; r += v_i^2 (15 adds), where
// the chain's elements are c0, c0+8, ..., c0+120 (element index * stride).
// ---------------------------------------------------------------------------
__device__ __forceinline__ float sqchain(const float* __restrict__ base, int stride, int c0) {
    float v = base[(size_t)c0 * stride];
    float r = __fmul_rn(v, v);
#pragma unroll
    for (int i = 1; i < 16; ++i) {
        float u = base[(size_t)(c0 + 8 * i) * stride];
        r = __fadd_rn(r, __fmul_rn(u, u));
    }
    return r;
}

// ---------------------------------------------------------------------------
// Kernel 1: numpy-pairwise sums of squares, coalesced (proven round 3).
// 4 threads per row; wave = 16 consecutive rows x 4 acc-groups.
// Exact numpy pairwise tree via commutative fadd butterflies.
// Also inits ws64 argmin slots and the loss accumulator.
// ---------------------------------------------------------------------------
__global__ void vq_sums(const float* __restrict__ in, const float* __restrict__ emb,
                        float* __restrict__ sx_arr, float* __restrict__ se_arr,
                        float* __restrict__ loss_acc,
                        unsigned long long* __restrict__ ws64) {
    const int tid  = threadIdx.x;
    const int wave = tid >> 6;
    const int lane = tid & 63;
    const int jg   = lane >> 4;      // acc-group 0..3
    const int p    = lane & 15;      // row-in-wave
    const int n    = blockIdx.x * 64 + wave * 16 + p;
    if (blockIdx.x == 0 && tid == 0) *loss_acc = 0.0f;

    const float* base;
    int stride;
    if (n < NPIX) {
        base = in + (size_t)(n >> 10) * BSTRIDE + (n & 1023);
        stride = 1024;
    } else {
        base = emb + (size_t)(n - NPIX) * DIM;
        stride = 1;
    }
    const int c0 = 2 * jg;
    float glo = __fadd_rn(sqchain(base, stride, c0),       sqchain(base, stride, c0 + 1));
    float ghi = __fadd_rn(sqchain(base, stride, 128 + c0), sqchain(base, stride, 128 + c0 + 1));
    glo = __fadd_rn(glo, __shfl_xor(glo, 16, 64));
    glo = __fadd_rn(glo, __shfl_xor(glo, 32, 64));
    ghi = __fadd_rn(ghi, __shfl_xor(ghi, 16, 64));
    ghi = __fadd_rn(ghi, __shfl_xor(ghi, 32, 64));
    float s = __fadd_rn(glo, ghi);   // pw256 = pw128_lo + pw128_hi

    if (jg == 0) {
        if (n < NPIX) {
            sx_arr[n] = s;
            ws64[n] = 0xFFFFFFFFFFFFFFFFull;
        } else {
            se_arr[n - NPIX] = s;
        }
    }
}

// monotone float -> uint32 key (total order preserved for finite floats)
__device__ __forceinline__ unsigned int f2key(float f) {
    unsigned int u = __float_as_uint(f);
    return (u & 0x80000000u) ? ~u : (u | 0x80000000u);
}

// ---------------------------------------------------------------------------
// Kernel 2: split-K=4 argmin GEMM.
// grid = 1024: bx&255 -> n-tile (128 pixels), bx>>8 -> k-quarter (256 codes).
// block = 256 (tx = k dim 16, ty = n dim 16), 8x8 microtile.
// REGISTER DISCIPLINE (round-1 proven, NO float4 fold loads): scalar sx[8]
// loaded once; scalar se[8] per k-tile. Live set ~96 (acc 64 + sx 8 + se 8 +
// bmin/bidx 16) -> ~120 VGPR, no spill. Round 3's float4 sxv/sev fold loads
// stretched 16 extra live ranges across the dc-loop -> acc spilled (127 MB
// scratch writes). Do not reintroduce.
// b-frag mapping: thread tx owns k-locals {tx*4+c, 64+tx*4+c} -> b128 reads
// 2-way bank aliasing (free). es stores 2-way. xs reads broadcast.
// Accumulation: fp32 fmac over d = 0..255 ascending (bit-stable, verified).
// Fold: d = round(round(sx - 2m) + se); ties -> smaller k.
// ---------------------------------------------------------------------------
__global__ __launch_bounds__(256, 2)
void vq_argmin(const float* __restrict__ in, const float* __restrict__ emb,
               const float* __restrict__ sx_arr, const float* __restrict__ se_arr,
               unsigned long long* __restrict__ ws64) {
    const int bx = blockIdx.x;
    const int nt = bx & 255;
    const int ks = bx >> 8;
    const int n0 = nt << 7;          // 128 pixels per tile
    const int b  = n0 >> 10;
    const int hw0 = n0 & 1023;
    const int tid = threadIdx.x;
    const int tx = tid & 15;
    const int ty = tid >> 4;

    __shared__ float xs[16][128];
    __shared__ float es[16][132];     // +4 pad keeps transposed stores 2-way

    float sx[8];
#pragma unroll
    for (int i = 0; i < 8; ++i) sx[i] = sx_arr[n0 + ty * 8 + i];

    float bmin[8];
    int   bidx[8];
#pragma unroll
    for (int i = 0; i < 8; ++i) { bmin[i] = __uint_as_float(0x7f800000u); bidx[i] = 0; }

    const float* xbase = in + (size_t)b * BSTRIDE + hw0;

    for (int kt = 0; kt < 2; ++kt) {
        const int k0 = ks * 256 + kt * 128;
        float se[8];
#pragma unroll
        for (int j = 0; j < 8; ++j) se[j] = se_arr[k0 + tx * 4 + (j & 3) + 64 * (j >> 2)];

        float acc[8][8];
#pragma unroll
        for (int i = 0; i < 8; ++i)
#pragma unroll
            for (int j = 0; j < 8; ++j) acc[i][j] = 0.0f;

        for (int dc = 0; dc < 16; ++dc) {
            const int d0 = dc * 16;
            __syncthreads();   // previous-iteration readers done
            // stage x: 16 d x 128 n, coalesced along n
            {
                const int n4 = (tid & 31) * 4;
                const int dd = tid >> 5;
#pragma unroll
                for (int p = 0; p < 2; ++p) {
                    const int d = dd + 8 * p;
                    float4 v = *(const float4*)(xbase + (size_t)(d0 + d) * 1024 + n4);
                    *(float4*)&xs[d][n4] = v;
                }
            }
            // stage e (transposed): 128 k x 16 d
            {
                const int dq = (tid & 3) * 4;
                const int kb = tid >> 2;
#pragma unroll
                for (int p = 0; p < 2; ++p) {
                    const int k_l = kb + 64 * p;
                    float4 v = *(const float4*)(emb + (size_t)(k0 + k_l) * DIM + d0 + dq);
                    es[dq + 0][k_l] = v.x;
                    es[dq + 1][k_l] = v.y;
                    es[dq + 2][k_l] = v.z;
                    es[dq + 3][k_l] = v.w;
                }
            }
            __syncthreads();
#pragma unroll
            for (int d = 0; d < 16; ++d) {
                float4 a0 = *(const float4*)&xs[d][ty * 8];
                float4 a1 = *(const float4*)&xs[d][ty * 8 + 4];
                float4 b0 = *(const float4*)&es[d][tx * 4];        // k-locals tx*4..tx*4+3
                float4 b1 = *(const float4*)&es[d][tx * 4 + 64];   // k-locals 64+tx*4..+3
                float av[8] = {a0.x, a0.y, a0.z, a0.w, a1.x, a1.y, a1.z, a1.w};
                float bv[8] = {b0.x, b0.y, b0.z, b0.w, b1.x, b1.y, b1.z, b1.w};
#pragma unroll
                for (int i = 0; i < 8; ++i)
#pragma unroll
                    for (int j = 0; j < 8; ++j)
                        acc[i][j] += av[i] * bv[j];
            }
        }
        // fold this k-tile into running per-thread argmin (numpy-faithful rounding)
#pragma unroll
        for (int i = 0; i < 8; ++i) {
#pragma unroll
            for (int j = 0; j < 8; ++j) {
                float t  = __fmaf_rn(-2.0f, acc[i][j], sx[i]);   // round(sx - 2m)
                float dv = __fadd_rn(t, se[j]);                  // round(+ se)
                int   k  = k0 + tx * 4 + (j & 3) + 64 * (j >> 2);
                if (dv < bmin[i]) { bmin[i] = dv; bidx[i] = k; } // j ascending == k ascending
            }
        }
    }

    // intra-wave reduction across tx (16 lanes per pixel-group), tie -> smaller k
#pragma unroll
    for (int i = 0; i < 8; ++i) {
        float v = bmin[i];
        int   k = bidx[i];
#pragma unroll
        for (int m = 1; m < 16; m <<= 1) {
            float ov = __shfl_xor(v, m, 16);
            int   ok = __shfl_xor(k, m, 16);
            if (ov < v || (ov == v && ok < k)) { v = ov; k = ok; }
        }
        if (tx == 0) {
            unsigned long long packed = ((unsigned long long)f2key(v) << 32) | (unsigned int)k;
            atomicMin(&ws64[n0 + ty * 8 + i], packed);
        }
    }
}

// ---------------------------------------------------------------------------
// Kernel 3: gather quantized rows, write straight-through output + indices,
// accumulate loss sum. grid = 256 blocks x 256 threads, 128 n per block.
// ---------------------------------------------------------------------------
__global__ void vq_write(const float* __restrict__ in, const float* __restrict__ emb,
                         const unsigned long long* __restrict__ ws64,
                         float* __restrict__ out0, float* __restrict__ out2,
                         float* __restrict__ loss_acc) {
    const int nt = blockIdx.x;
    const int n0 = nt << 7;
    const int b  = n0 >> 10;
    const int hw0 = n0 & 1023;
    const int tid = threadIdx.x;
    const int n_l = tid & 127;
    const int ch0 = tid >> 7;

    const int k = (int)(unsigned int)(ws64[n0 + n_l] & 0xFFFFFFFFull);
    if (tid < 128) out2[n0 + tid] = (float)k;

    const float* xrow = in  + (size_t)b * BSTRIDE + hw0 + n_l;
    float*       orow = out0 + (size_t)b * BSTRIDE + hw0 + n_l;
    const float* erow = emb + (size_t)k * DIM;

    float lsum = 0.0f;
    for (int it = 0; it < 128; ++it) {
        const int ch = it * 2 + ch0;
        float x = xrow[(size_t)ch * 1024];
        float q = erow[ch];
        float df = __fsub_rn(q, x);                 // round(q - x)
        orow[(size_t)ch * 1024] = __fadd_rn(x, df); // straight-through value
        lsum = __fadd_rn(lsum, __fmul_rn(df, df));
    }
    // block reduction: wave shuffle then LDS across 4 waves
#pragma unroll
    for (int off = 32; off >= 1; off >>= 1)
        lsum += __shfl_down(lsum, off, 64);
    __shared__ float wsum[4];
    if ((tid & 63) == 0) wsum[tid >> 6] = lsum;
    __syncthreads();
    if (tid == 0) {
        float t = wsum[0] + wsum[1] + wsum[2] + wsum[3];
        atomicAdd(loss_acc, t);
    }
}

// ---------------------------------------------------------------------------
// Kernel 4: finalize loss. mean = sum * 2^-23 (exact), loss = e + 0.25*e.
// ---------------------------------------------------------------------------
__global__ void vq_loss(const float* __restrict__ loss_acc, float* __restrict__ out1) {
    float s = *loss_acc;
    float e = s * (1.0f / 8388608.0f);      // division by 2^23, exact scaling
    out1[0] = __fadd_rn(e, __fmul_rn(0.25f, e));
}

extern "C" void kernel_launch(void* const* d_in, const int* in_sizes, int n_in,
                              void* d_out, int out_size, void* d_ws, size_t ws_size,
                              hipStream_t stream) {
    const float* in  = (const float*)d_in[0];
    const float* emb = (const float*)d_in[1];
    float* out = (float*)d_out;

    unsigned long long* ws64 = (unsigned long long*)d_ws;          // 32768 * 8 B
    float* wsf     = (float*)((char*)d_ws + NPIX * sizeof(unsigned long long));
    float* lossacc = wsf;                 // [0]
    float* sx_arr  = wsf + 256;           // 32768 floats
    float* se_arr  = wsf + 256 + NPIX;    // 1024 floats

    // vq_sums also inits ws64 (argmin slots) and the loss accumulator.
    vq_sums<<<(NPIX + KCODE) / 64, 256, 0, stream>>>(in, emb, sx_arr, se_arr, lossacc, ws64);
    vq_argmin<<<1024, 256, 0, stream>>>(in, emb, sx_arr, se_arr, ws64);
    vq_write<<<256, 256, 0, stream>>>(in, emb, ws64, out, out + OUT0_N + 1, lossacc);
    vq_loss<<<1, 1, 0, stream>>>(lossacc, out + OUT0_N);
}